// Round 14
// baseline (123.961 us; speedup 1.0000x reference)
//
#include <hip/hip_runtime.h>
#include <hip/hip_bf16.h>

// MultiHeadAttention: x(16,512,256) f32; mask(1,16,512,512) bool; adj(1,16,512,512) f32;
// Wq/Wk/Wv (256,256) f32.  out = softmax(QK^T/sqrt(64) + adj, mask) @ V + x, f32.
// R13: same per-wave work as R11 (split-K pair, s[8], online softmax) but
// block=128 (one pair) + launch_bounds(128,6): VGPR cap 512/6~85 >= ~60
// pressure (no spill) while requesting 24 waves/CU (R11's (256,4) contract
// self-capped at ~16/CU -> measured 13). Detect-mask folded into attn waves.

#define NB 16
#define NA 512
#define HID 256
#define NHEAD 8
#define DH 32
#define INV_TP 0.125f  // 1/sqrt(2*32)

typedef __attribute__((ext_vector_type(8))) short short8;   // 8 bf16 MFMA frag
typedef __attribute__((ext_vector_type(4))) float floatx4;  // MFMA acc

__device__ __forceinline__ unsigned short f2bf(float f) {
  unsigned int u = __builtin_bit_cast(unsigned int, f);
  u += 0x7fffu + ((u >> 16) & 1u);  // round-to-nearest-even
  return (unsigned short)(u >> 16);
}

__device__ __forceinline__ floatx4 mfma16(short8 a, short8 b, floatx4 c) {
  return __builtin_amdgcn_mfma_f32_16x16x32_bf16(a, b, c, 0, 0, 0);
}

__device__ __forceinline__ short8 ld8f32_bf16(const float* __restrict__ p) {
  float4 a = *(const float4*)p;
  float4 b = *(const float4*)(p + 4);
  short8 r;
  r[0] = (short)f2bf(a.x); r[1] = (short)f2bf(a.y);
  r[2] = (short)f2bf(a.z); r[3] = (short)f2bf(a.w);
  r[4] = (short)f2bf(b.x); r[5] = (short)f2bf(b.y);
  r[6] = (short)f2bf(b.z); r[7] = (short)f2bf(b.w);
  return r;
}

// Y[m][c] = sum_k X[m][k] * W[c][k].
// Q,K stored [b][h][n][d]; V stored TRANSPOSED [b][h][d][n].
// 32-row tiles, grid (256,3) = 768 blocks.
__global__ __launch_bounds__(256) void qkv_proj(
    const float* __restrict__ X, const float* __restrict__ Wq,
    const float* __restrict__ Wk, const float* __restrict__ Wv,
    unsigned short* __restrict__ Y) {
  const float* W = (blockIdx.y == 0) ? Wq : (blockIdx.y == 1) ? Wk : Wv;
  unsigned short* Yo = Y + (size_t)blockIdx.y * (NB * NHEAD * NA * DH);
  const int wave = threadIdx.x >> 6, lane = threadIdx.x & 63;
  const int lr = lane & 15, lh = lane >> 4;
  const int m0 = blockIdx.x * 32;
  const int cb = wave * 64;
  const floatx4 z = {0.f, 0.f, 0.f, 0.f};
  floatx4 acc[2][4];
#pragma unroll
  for (int i = 0; i < 2; i++)
#pragma unroll
    for (int j = 0; j < 4; j++) acc[i][j] = z;

  for (int kb = 0; kb < HID; kb += 32) {
    short8 a[2], bw[4];
#pragma unroll
    for (int rt = 0; rt < 2; rt++)
      a[rt] = ld8f32_bf16(X + (size_t)(m0 + rt * 16 + lr) * HID + kb + lh * 8);
#pragma unroll
    for (int ci = 0; ci < 4; ci++)
      bw[ci] = ld8f32_bf16(W + (size_t)(cb + ci * 16 + lr) * HID + kb + lh * 8);
#pragma unroll
    for (int rt = 0; rt < 2; rt++)
#pragma unroll
      for (int ci = 0; ci < 4; ci++)
        acc[rt][ci] = mfma16(a[rt], bw[ci], acc[rt][ci]);
  }
  if (blockIdx.y == 2) {
    // V: [b][h][d][n], 4 consecutive n (rows m..m+3) packed per store.
#pragma unroll
    for (int rt = 0; rt < 2; rt++)
#pragma unroll
      for (int ci = 0; ci < 4; ci++) {
        int m = m0 + rt * 16 + lh * 4;       // rows m..m+3 (same batch: 32|512)
        int c = cb + ci * 16 + lr;
        int bb = m >> 9, n0 = m & 511, hh = c >> 5, dd = c & 31;
        ushort4 w;
        w.x = f2bf(acc[rt][ci][0]);
        w.y = f2bf(acc[rt][ci][1]);
        w.z = f2bf(acc[rt][ci][2]);
        w.w = f2bf(acc[rt][ci][3]);
        *(ushort4*)&Yo[((size_t)(bb * NHEAD + hh) * DH + dd) * NA + n0] = w;
      }
  } else {
#pragma unroll
    for (int rt = 0; rt < 2; rt++)
#pragma unroll
      for (int ci = 0; ci < 4; ci++)
#pragma unroll
        for (int r = 0; r < 4; r++) {
          int m = m0 + rt * 16 + lh * 4 + r;   // D layout: row=(l>>4)*4+reg
          int c = cb + ci * 16 + lr;           //           col=l&15
          int bb = m >> 9, n = m & 511, hh = c >> 5, dd = c & 31;
          Yo[((size_t)(bb * NHEAD + hh) * NA + n) * DH + dd] = f2bf(acc[rt][ci][r]);
        }
  }
}

// grid: (32 q-blocks of 16 rows, 8 heads, 16 batch) = 4096 blocks, 128 thr.
// Block = one split-K pair: wave hv in {0,1} covers keys hv*256..hv*256+256
// (2 tiles of 128, online softmax); halves merge via 4.5KB LDS.
__global__ __launch_bounds__(128, 6) void attn_fused(
    const unsigned short* __restrict__ Qw, const unsigned short* __restrict__ Kw,
    const unsigned short* __restrict__ Vtg, const float* __restrict__ X,
    const unsigned char* __restrict__ maskB, const int* __restrict__ maskI,
    const float* __restrict__ adj, float* __restrict__ out) {
  __shared__ float lds_o[2][16][33];  // [half][row][col(+pad)]
  __shared__ float lds_m[2][16];
  __shared__ float lds_l[2][16];
  const int qb = blockIdx.x, h = blockIdx.y, b = blockIdx.z;
  const int t = threadIdx.x;
  const int hv = t >> 6, lane = t & 63, lr = lane & 15, lh = lane >> 4;
  const int q0 = qb * 16;
  const size_t bh = (size_t)(b * NHEAD + h) * NA * DH;
  const unsigned short* Kg = Kw + bh;
  const unsigned short* Vg = Vtg + bh;  // [d][n]: d*NA + n

  // inline mask-dtype detect: count nonzero among first 512 uint32 words.
  // bool bytes: E=480/512; int32 0/1: E=256/512; threshold 368 (>10 sigma).
  {
  }
  const unsigned int* mu = (const unsigned int*)maskB;
  unsigned int cnt = 0;
#pragma unroll
  for (int j = 0; j < 8; j++) cnt += (mu[lane + j * 64] != 0u) ? 1u : 0u;
#pragma unroll
  for (int off = 32; off > 0; off >>= 1) cnt += __shfl_xor(cnt, off);
  const bool mBytes = (cnt > 368u);

  short8 qf = *(const short8*)&Qw[bh + (size_t)(q0 + lr) * DH + lh * 8];
  const floatx4 z = {0.f, 0.f, 0.f, 0.f};

  const int q = q0 + lr;
  const size_t rowoff = ((size_t)b * NA + q) * NA;
  const float* adjRow = adj + rowoff;

  float m_run = -3.0e38f, l_run = 0.f;  // state for q = q0 + lr (S^T layout)
  floatx4 o0 = z, o1 = z;               // rows q0 + lh*4 + r (C/D layout)

#pragma unroll
  for (int tile = 0; tile < 2; ++tile) {
    const int keyoff = hv * 256 + tile * 128;
    // S^T = K * Q^T: lane holds col q=lr, rows key=keyoff+kt*16+lh*4+r
    floatx4 s[8];
#pragma unroll
    for (int kt = 0; kt < 8; kt++) s[kt] = z;
#pragma unroll
    for (int kt = 0; kt < 8; kt++) {
      short8 kf = *(const short8*)&Kg[(size_t)(keyoff + kt * 16 + lr) * DH + lh * 8];
      s[kt] = mfma16(kf, qf, s[kt]);
    }

    float pmax = -3.0e38f;
#pragma unroll
    for (int kt = 0; kt < 8; kt++) {
      const int k0 = keyoff + kt * 16 + lh * 4;  // 4 consecutive keys per lane
      float4 av = *(const float4*)&adjRow[k0];
      float v0 = s[kt][0] * INV_TP + av.x;
      float v1 = s[kt][1] * INV_TP + av.y;
      float v2 = s[kt][2] * INV_TP + av.z;
      float v3 = s[kt][3] * INV_TP + av.w;
      if (mBytes) {
        uchar4 mb = *(const uchar4*)&maskB[rowoff + k0];
        if (mb.x) v0 = -1e30f;
        if (mb.y) v1 = -1e30f;
        if (mb.z) v2 = -1e30f;
        if (mb.w) v3 = -1e30f;
      } else {
        int4 mi = *(const int4*)&maskI[rowoff + k0];
        if (mi.x) v0 = -1e30f;
        if (mi.y) v1 = -1e30f;
        if (mi.z) v2 = -1e30f;
        if (mi.w) v3 = -1e30f;
      }
      s[kt][0] = v0; s[kt][1] = v1; s[kt][2] = v2; s[kt][3] = v3;
      pmax = fmaxf(pmax, fmaxf(fmaxf(v0, v1), fmaxf(v2, v3)));
    }
    // row q lives in lanes {lr, lr+16, lr+32, lr+48}
    pmax = fmaxf(pmax, __shfl_xor(pmax, 16));
    pmax = fmaxf(pmax, __shfl_xor(pmax, 32));

    const float mnew = fmaxf(m_run, pmax);
    if (tile) {  // tile 0: o/l are zero, skip rescale (shorter chain)
      const float corr = __expf(m_run - mnew);
      l_run *= corr;
#pragma unroll
      for (int r = 0; r < 4; r++) {
        float c = __shfl(corr, lh * 4 + r, 64);
        o0[r] *= c;
        o1[r] *= c;
      }
    }
    m_run = mnew;

    float sum = 0.f;
#pragma unroll
    for (int kt = 0; kt < 8; kt++) {
      float e0 = __expf(s[kt][0] - mnew);
      float e1 = __expf(s[kt][1] - mnew);
      float e2 = __expf(s[kt][2] - mnew);
      float e3 = __expf(s[kt][3] - mnew);
      s[kt][0] = e0; s[kt][1] = e1; s[kt][2] = e2; s[kt][3] = e3;
      sum += (e0 + e1) + (e2 + e3);
    }
    sum += __shfl_xor(sum, 16);
    sum += __shfl_xor(sum, 32);
    l_run += sum;

    // PV, relabeled K-dim: slot lh*8+j <-> key keyoff+32kc+(j<4 ? lh*4+j : 16+lh*4+j-4).
#pragma unroll
    for (int kc = 0; kc < 4; kc++) {
      union { short8 s8; unsigned int u[4]; } aa;
      aa.u[0] = (unsigned int)f2bf(s[2 * kc][0]) |
                ((unsigned int)f2bf(s[2 * kc][1]) << 16);
      aa.u[1] = (unsigned int)f2bf(s[2 * kc][2]) |
                ((unsigned int)f2bf(s[2 * kc][3]) << 16);
      aa.u[2] = (unsigned int)f2bf(s[2 * kc + 1][0]) |
                ((unsigned int)f2bf(s[2 * kc + 1][1]) << 16);
      aa.u[3] = (unsigned int)f2bf(s[2 * kc + 1][2]) |
                ((unsigned int)f2bf(s[2 * kc + 1][3]) << 16);
      const int kbase = keyoff + kc * 32 + lh * 4;
      union { short8 s8; uint2 u2[2]; } v0f, v1f;
      v0f.u2[0] = *(const uint2*)&Vg[(size_t)lr * NA + kbase];
      v0f.u2[1] = *(const uint2*)&Vg[(size_t)lr * NA + kbase + 16];
      v1f.u2[0] = *(const uint2*)&Vg[(size_t)(16 + lr) * NA + kbase];
      v1f.u2[1] = *(const uint2*)&Vg[(size_t)(16 + lr) * NA + kbase + 16];
      o0 = mfma16(aa.s8, v0f.s8, o0);
      o1 = mfma16(aa.s8, v1f.s8, o1);
    }
  }

  // publish partials: o rows are q0+lh*4+r (C/D), m/l are per q=q0+lr (S^T)
#pragma unroll
  for (int r = 0; r < 4; r++) {
    lds_o[hv][lh * 4 + r][lr] = o0[r];
    lds_o[hv][lh * 4 + r][16 + lr] = o1[r];
  }
  if (lane < 16) {
    lds_m[hv][lane] = m_run;
    lds_l[hv][lane] = l_run;
  }
  __syncthreads();

  // merge: wave hv handles col-half hv of the 16x32 output tile.
#pragma unroll
  for (int r = 0; r < 4; r++) {
    const int row = lh * 4 + r;
    float mA = lds_m[0][row], mB = lds_m[1][row];
    float lA = lds_l[0][row], lB = lds_l[1][row];
    float ms = fmaxf(mA, mB);
    float cA = __expf(mA - ms), cB = __expf(mB - ms);
    float linv = 1.0f / (lA * cA + lB * cB);
    float oA = lds_o[0][row][hv * 16 + lr];
    float oB = lds_o[1][row][hv * 16 + lr];
    size_t idx = ((size_t)b * NA + (q0 + row)) * HID + h * DH + hv * 16 + lr;
    out[idx] = (oA * cA + oB * cB) * linv + X[idx];
  }
}

extern "C" void kernel_launch(void* const* d_in, const int* in_sizes, int n_in,
                              void* d_out, int out_size, void* d_ws, size_t ws_size,
                              hipStream_t stream) {
  const float* x = (const float*)d_in[0];
  const void* mask = d_in[1];
  const float* adj = (const float*)d_in[2];
  const float* Wq = (const float*)d_in[3];
  const float* Wk = (const float*)d_in[4];
  const float* Wv = (const float*)d_in[5];
  float* out = (float*)d_out;

  char* ws = (char*)d_ws;
  unsigned short* Qw = (unsigned short*)(ws + 4096);                 // 4 MB
  unsigned short* Kw = (unsigned short*)(ws + 4096 + 4194304);      // 4 MB
  unsigned short* Vw = (unsigned short*)(ws + 4096 + 2 * 4194304); // 4 MB (transposed)
  // requires ws_size >= ~12.6 MB

  qkv_proj<<<dim3(256, 3), 256, 0, stream>>>(x, Wq, Wk, Wv, Qw);
  attn_fused<<<dim3(32, NHEAD, NB), 128, 0, stream>>>(
      Qw, Kw, Vw, x, (const unsigned char*)mask, (const int*)mask, adj, out);
}

// Round 15
// 82.520 us; speedup vs baseline: 1.5022x; 1.5022x over previous
//
#include <hip/hip_runtime.h>
#include <hip/hip_bf16.h>

// MultiHeadAttention: x(16,512,256) f32; mask(1,16,512,512) bool; adj(1,16,512,512) f32;
// Wq/Wk/Wv (256,256) f32.  out = softmax(QK^T/sqrt(64) + adj, mask) @ V + x, f32.
// R14: adj/mask are head-independent -> block = (b, 16 q-rows) x 8 heads (512 thr,
// wave=head). Bias tile (16x128, mask pre-merged to -1e30) staged cooperatively
// into double-buffered LDS; loads for t+1 issued before compute of t. Cuts bias
// global traffic 8x and turns the 16 load-use latency pairs/tile into ds_reads.
// Per-wave math = R9 (4 tiles of 128, s[8], online softmax, no spill at cap 64).

#define NB 16
#define NA 512
#define HID 256
#define NHEAD 8
#define DH 32
#define INV_TP 0.125f  // 1/sqrt(2*32)
#define ADJ_LD 132     // 16x128 f32 tile, rows padded to 132 (optimal-throughput reads)

typedef __attribute__((ext_vector_type(8))) short short8;   // 8 bf16 MFMA frag
typedef __attribute__((ext_vector_type(4))) float floatx4;  // MFMA acc

__device__ __forceinline__ unsigned short f2bf(float f) {
  unsigned int u = __builtin_bit_cast(unsigned int, f);
  u += 0x7fffu + ((u >> 16) & 1u);  // round-to-nearest-even
  return (unsigned short)(u >> 16);
}

__device__ __forceinline__ floatx4 mfma16(short8 a, short8 b, floatx4 c) {
  return __builtin_amdgcn_mfma_f32_16x16x32_bf16(a, b, c, 0, 0, 0);
}

__device__ __forceinline__ short8 ld8f32_bf16(const float* __restrict__ p) {
  float4 a = *(const float4*)p;
  float4 b = *(const float4*)(p + 4);
  short8 r;
  r[0] = (short)f2bf(a.x); r[1] = (short)f2bf(a.y);
  r[2] = (short)f2bf(a.z); r[3] = (short)f2bf(a.w);
  r[4] = (short)f2bf(b.x); r[5] = (short)f2bf(b.y);
  r[6] = (short)f2bf(b.z); r[7] = (short)f2bf(b.w);
  return r;
}

// Y[m][c] = sum_k X[m][k] * W[c][k].
// Q,K stored [b][h][n][d]; V stored TRANSPOSED [b][h][d][n].
// 32-row tiles, grid (256,3) = 768 blocks.
__global__ __launch_bounds__(256) void qkv_proj(
    const float* __restrict__ X, const float* __restrict__ Wq,
    const float* __restrict__ Wk, const float* __restrict__ Wv,
    unsigned short* __restrict__ Y) {
  const float* W = (blockIdx.y == 0) ? Wq : (blockIdx.y == 1) ? Wk : Wv;
  unsigned short* Yo = Y + (size_t)blockIdx.y * (NB * NHEAD * NA * DH);
  const int wave = threadIdx.x >> 6, lane = threadIdx.x & 63;
  const int lr = lane & 15, lh = lane >> 4;
  const int m0 = blockIdx.x * 32;
  const int cb = wave * 64;
  const floatx4 z = {0.f, 0.f, 0.f, 0.f};
  floatx4 acc[2][4];
#pragma unroll
  for (int i = 0; i < 2; i++)
#pragma unroll
    for (int j = 0; j < 4; j++) acc[i][j] = z;

  for (int kb = 0; kb < HID; kb += 32) {
    short8 a[2], bw[4];
#pragma unroll
    for (int rt = 0; rt < 2; rt++)
      a[rt] = ld8f32_bf16(X + (size_t)(m0 + rt * 16 + lr) * HID + kb + lh * 8);
#pragma unroll
    for (int ci = 0; ci < 4; ci++)
      bw[ci] = ld8f32_bf16(W + (size_t)(cb + ci * 16 + lr) * HID + kb + lh * 8);
#pragma unroll
    for (int rt = 0; rt < 2; rt++)
#pragma unroll
      for (int ci = 0; ci < 4; ci++)
        acc[rt][ci] = mfma16(a[rt], bw[ci], acc[rt][ci]);
  }
  if (blockIdx.y == 2) {
    // V: [b][h][d][n], 4 consecutive n (rows m..m+3) packed per store.
#pragma unroll
    for (int rt = 0; rt < 2; rt++)
#pragma unroll
      for (int ci = 0; ci < 4; ci++) {
        int m = m0 + rt * 16 + lh * 4;       // rows m..m+3 (same batch: 32|512)
        int c = cb + ci * 16 + lr;
        int bb = m >> 9, n0 = m & 511, hh = c >> 5, dd = c & 31;
        ushort4 w;
        w.x = f2bf(acc[rt][ci][0]);
        w.y = f2bf(acc[rt][ci][1]);
        w.z = f2bf(acc[rt][ci][2]);
        w.w = f2bf(acc[rt][ci][3]);
        *(ushort4*)&Yo[((size_t)(bb * NHEAD + hh) * DH + dd) * NA + n0] = w;
      }
  } else {
#pragma unroll
    for (int rt = 0; rt < 2; rt++)
#pragma unroll
      for (int ci = 0; ci < 4; ci++)
#pragma unroll
        for (int r = 0; r < 4; r++) {
          int m = m0 + rt * 16 + lh * 4 + r;   // D layout: row=(l>>4)*4+reg
          int c = cb + ci * 16 + lr;           //           col=l&15
          int bb = m >> 9, n = m & 511, hh = c >> 5, dd = c & 31;
          Yo[((size_t)(bb * NHEAD + hh) * NA + n) * DH + dd] = f2bf(acc[rt][ci][r]);
        }
  }
}

// grid: (32 q-blocks of 16 rows, 16 batch) = 512 blocks (2/CU exact), 512 thr.
// Wave h handles head h over all 512 keys (4 tiles of 128, online softmax).
// Bias tile (adj+mask merged) double-buffered in LDS, staged by all 512 threads.
__global__ __launch_bounds__(512, 4) void attn_fused(
    const unsigned short* __restrict__ Qw, const unsigned short* __restrict__ Kw,
    const unsigned short* __restrict__ Vtg, const float* __restrict__ X,
    const unsigned char* __restrict__ maskB, const int* __restrict__ maskI,
    const float* __restrict__ adj, float* __restrict__ out) {
  __shared__ float adj_lds[2][16][ADJ_LD];  // 2 x 8448 B
  const int qb = blockIdx.x, b = blockIdx.y;
  const int t = threadIdx.x;
  const int h = t >> 6, lane = t & 63, lr = lane & 15, lh = lane >> 4;
  const int q0 = qb * 16;
  const size_t bh = (size_t)(b * NHEAD + h) * NA * DH;
  const unsigned short* Kg = Kw + bh;
  const unsigned short* Vg = Vtg + bh;  // [d][n]: d*NA + n

  // mask dtype detect (wave-level over first 512 words; wave-uniform result).
  // bool bytes: E=480/512 nonzero; int32 0/1: E=256/512; threshold 368.
  const unsigned int* mu = (const unsigned int*)maskB;
  unsigned int cnt = 0;
#pragma unroll
  for (int j = 0; j < 8; j++) cnt += (mu[lane + j * 64] != 0u) ? 1u : 0u;
#pragma unroll
  for (int off = 32; off > 0; off >>= 1) cnt += __shfl_xor(cnt, off);
  const bool mBytes = (cnt > 368u);

  // staging: thread t owns float4 #t of the 16x128 bias tile.
  const int srow = t >> 5, sc4 = (t & 31) * 4;
  const size_t srowoff = ((size_t)b * NA + q0 + srow) * NA;

  // prologue: stage tile 0 (mask merged: masked -> -1e30)
  {
    float4 av = *(const float4*)&adj[srowoff + sc4];
    if (mBytes) {
      uchar4 mb = *(const uchar4*)&maskB[srowoff + sc4];
      if (mb.x) av.x = -1e30f;
      if (mb.y) av.y = -1e30f;
      if (mb.z) av.z = -1e30f;
      if (mb.w) av.w = -1e30f;
    } else {
      int4 mi = *(const int4*)&maskI[srowoff + sc4];
      if (mi.x) av.x = -1e30f;
      if (mi.y) av.y = -1e30f;
      if (mi.z) av.z = -1e30f;
      if (mi.w) av.w = -1e30f;
    }
    *(float4*)&adj_lds[0][srow][sc4] = av;
  }
  __syncthreads();

  short8 qf = *(const short8*)&Qw[bh + (size_t)(q0 + lr) * DH + lh * 8];
  const floatx4 z = {0.f, 0.f, 0.f, 0.f};

  float m_run = -3.0e38f, l_run = 0.f;  // state for q = q0 + lr (S^T layout)
  floatx4 o0 = z, o1 = z;               // rows q0 + lh*4 + r (C/D layout)

#pragma unroll
  for (int tile = 0; tile < 4; ++tile) {
    const int cur = tile & 1;
    const int keyoff = tile * 128;

    // issue next-tile bias loads early (vmcnt waits after compute = T14 split)
    float4 nav;
    uchar4 nmbB;
    int4 nmbI;
    if (tile < 3) {
      const int nko = (tile + 1) * 128;
      nav = *(const float4*)&adj[srowoff + nko + sc4];
      if (mBytes) nmbB = *(const uchar4*)&maskB[srowoff + nko + sc4];
      else        nmbI = *(const int4*)&maskI[srowoff + nko + sc4];
    }

    // S^T = K * Q^T: lane holds col q=lr, rows key=keyoff+kt*16+lh*4+r
    floatx4 s[8];
#pragma unroll
    for (int kt = 0; kt < 8; kt++) s[kt] = z;
#pragma unroll
    for (int kt = 0; kt < 8; kt++) {
      short8 kf = *(const short8*)&Kg[(size_t)(keyoff + kt * 16 + lr) * DH + lh * 8];
      s[kt] = mfma16(kf, qf, s[kt]);
    }

    float pmax = -3.0e38f;
#pragma unroll
    for (int kt = 0; kt < 8; kt++) {
      // bias from LDS: row lr, cols kt*16+lh*4 (mask already merged)
      float4 av = *(const float4*)&adj_lds[cur][lr][kt * 16 + lh * 4];
      float v0 = s[kt][0] * INV_TP + av.x;
      float v1 = s[kt][1] * INV_TP + av.y;
      float v2 = s[kt][2] * INV_TP + av.z;
      float v3 = s[kt][3] * INV_TP + av.w;
      s[kt][0] = v0; s[kt][1] = v1; s[kt][2] = v2; s[kt][3] = v3;
      pmax = fmaxf(pmax, fmaxf(fmaxf(v0, v1), fmaxf(v2, v3)));
    }
    // row q lives in lanes {lr, lr+16, lr+32, lr+48}
    pmax = fmaxf(pmax, __shfl_xor(pmax, 16));
    pmax = fmaxf(pmax, __shfl_xor(pmax, 32));

    const float mnew = fmaxf(m_run, pmax);
    if (tile) {  // tile 0: o/l are zero, skip rescale
      const float corr = __expf(m_run - mnew);
      l_run *= corr;
#pragma unroll
      for (int r = 0; r < 4; r++) {
        float c = __shfl(corr, lh * 4 + r, 64);
        o0[r] *= c;
        o1[r] *= c;
      }
    }
    m_run = mnew;

    float sum = 0.f;
#pragma unroll
    for (int kt = 0; kt < 8; kt++) {
      float e0 = __expf(s[kt][0] - mnew);
      float e1 = __expf(s[kt][1] - mnew);
      float e2 = __expf(s[kt][2] - mnew);
      float e3 = __expf(s[kt][3] - mnew);
      s[kt][0] = e0; s[kt][1] = e1; s[kt][2] = e2; s[kt][3] = e3;
      sum += (e0 + e1) + (e2 + e3);
    }
    sum += __shfl_xor(sum, 16);
    sum += __shfl_xor(sum, 32);
    l_run += sum;

    // PV, relabeled K-dim: slot lh*8+j <-> key keyoff+32kc+(j<4 ? lh*4+j : 16+lh*4+j-4).
#pragma unroll
    for (int kc = 0; kc < 4; kc++) {
      union { short8 s8; unsigned int u[4]; } aa;
      aa.u[0] = (unsigned int)f2bf(s[2 * kc][0]) |
                ((unsigned int)f2bf(s[2 * kc][1]) << 16);
      aa.u[1] = (unsigned int)f2bf(s[2 * kc][2]) |
                ((unsigned int)f2bf(s[2 * kc][3]) << 16);
      aa.u[2] = (unsigned int)f2bf(s[2 * kc + 1][0]) |
                ((unsigned int)f2bf(s[2 * kc + 1][1]) << 16);
      aa.u[3] = (unsigned int)f2bf(s[2 * kc + 1][2]) |
                ((unsigned int)f2bf(s[2 * kc + 1][3]) << 16);
      const int kbase = keyoff + kc * 32 + lh * 4;
      union { short8 s8; uint2 u2[2]; } v0f, v1f;
      v0f.u2[0] = *(const uint2*)&Vg[(size_t)lr * NA + kbase];
      v0f.u2[1] = *(const uint2*)&Vg[(size_t)lr * NA + kbase + 16];
      v1f.u2[0] = *(const uint2*)&Vg[(size_t)(16 + lr) * NA + kbase];
      v1f.u2[1] = *(const uint2*)&Vg[(size_t)(16 + lr) * NA + kbase + 16];
      o0 = mfma16(aa.s8, v0f.s8, o0);
      o1 = mfma16(aa.s8, v1f.s8, o1);
    }

    // write staged tile t+1 into the other buffer, then block barrier
    if (tile < 3) {
      if (mBytes) {
        if (nmbB.x) nav.x = -1e30f;
        if (nmbB.y) nav.y = -1e30f;
        if (nmbB.z) nav.z = -1e30f;
        if (nmbB.w) nav.w = -1e30f;
      } else {
        if (nmbI.x) nav.x = -1e30f;
        if (nmbI.y) nav.y = -1e30f;
        if (nmbI.z) nav.z = -1e30f;
        if (nmbI.w) nav.w = -1e30f;
      }
      *(float4*)&adj_lds[cur ^ 1][srow][sc4] = nav;
    }
    __syncthreads();
  }

  const float inv = 1.0f / l_run;  // for q = q0 + lr
#pragma unroll
  for (int r = 0; r < 4; r++) {
    float iv = __shfl(inv, lh * 4 + r, 64);  // row q0+lh*4+r's normalizer
    size_t idx = ((size_t)b * NA + (q0 + lh * 4 + r)) * HID + h * DH + lr;
    out[idx] = o0[r] * iv + X[idx];
    out[idx + 16] = o1[r] * iv + X[idx + 16];
  }
}

extern "C" void kernel_launch(void* const* d_in, const int* in_sizes, int n_in,
                              void* d_out, int out_size, void* d_ws, size_t ws_size,
                              hipStream_t stream) {
  const float* x = (const float*)d_in[0];
  const void* mask = d_in[1];
  const float* adj = (const float*)d_in[2];
  const float* Wq = (const float*)d_in[3];
  const float* Wk = (const float*)d_in[4];
  const float* Wv = (const float*)d_in[5];
  float* out = (float*)d_out;

  char* ws = (char*)d_ws;
  unsigned short* Qw = (unsigned short*)(ws + 4096);                 // 4 MB
  unsigned short* Kw = (unsigned short*)(ws + 4096 + 4194304);      // 4 MB
  unsigned short* Vw = (unsigned short*)(ws + 4096 + 2 * 4194304); // 4 MB (transposed)
  // requires ws_size >= ~12.6 MB

  qkv_proj<<<dim3(256, 3), 256, 0, stream>>>(x, Wq, Wk, Wv, Qw);
  attn_fused<<<dim3(32, NB), 512, 0, stream>>>(
      Qw, Kw, Vw, x, (const unsigned char*)mask, (const int*)mask, adj, out);
}

// Round 16
// 73.467 us; speedup vs baseline: 1.6873x; 1.1232x over previous
//
#include <hip/hip_runtime.h>
#include <hip/hip_bf16.h>

// MultiHeadAttention: x(16,512,256) f32; mask(1,16,512,512) bool; adj(1,16,512,512) f32;
// Wq/Wk/Wv (256,256) f32.  out = softmax(QK^T/sqrt(64) + adj, mask) @ V + x, f32.
// R15: hoist f32->bf16 conversion out of the projection GEMM. cvt_bf16 converts
// X (4MB) + W (384KB) once (streaming, TLP-hidden); qkv_proj_bf is a pure bf16
// short8-load + MFMA loop (~200 VALU ops/wave vs ~2300 with inline cvt).
// attn_fused = R14 exactly (47us validated: bias shared across heads via LDS).
// Runtime ws_size check: needs 16.5MB; falls back to R14 f32-qkv path if small.

#define NB 16
#define NA 512
#define HID 256
#define NHEAD 8
#define DH 32
#define INV_TP 0.125f  // 1/sqrt(2*32)
#define ADJ_LD 132     // 16x128 f32 tile, rows padded to 132

typedef __attribute__((ext_vector_type(8))) short short8;   // 8 bf16 MFMA frag
typedef __attribute__((ext_vector_type(4))) float floatx4;  // MFMA acc

__device__ __forceinline__ unsigned short f2bf(float f) {
  unsigned int u = __builtin_bit_cast(unsigned int, f);
  u += 0x7fffu + ((u >> 16) & 1u);  // round-to-nearest-even
  return (unsigned short)(u >> 16);
}

__device__ __forceinline__ floatx4 mfma16(short8 a, short8 b, floatx4 c) {
  return __builtin_amdgcn_mfma_f32_16x16x32_bf16(a, b, c, 0, 0, 0);
}

__device__ __forceinline__ short8 ld8f32_bf16(const float* __restrict__ p) {
  float4 a = *(const float4*)p;
  float4 b = *(const float4*)(p + 4);
  short8 r;
  r[0] = (short)f2bf(a.x); r[1] = (short)f2bf(a.y);
  r[2] = (short)f2bf(a.z); r[3] = (short)f2bf(a.w);
  r[4] = (short)f2bf(b.x); r[5] = (short)f2bf(b.y);
  r[6] = (short)f2bf(b.z); r[7] = (short)f2bf(b.w);
  return r;
}

// Streaming f32->bf16 for X (2M elems) and Wq/Wk/Wv (64K each). Memory-bound;
// VALU cvt hidden by TLP (1024 blocks).
__global__ __launch_bounds__(256) void cvt_bf16(
    const float* __restrict__ X, const float* __restrict__ Wq,
    const float* __restrict__ Wk, const float* __restrict__ Wv,
    unsigned short* __restrict__ Xbf, unsigned short* __restrict__ Wbf) {
  const int tid = blockIdx.x * blockDim.x + threadIdx.x;
  const int stride = gridDim.x * blockDim.x;
  for (int i = tid; i < (NB * NA * HID) / 4; i += stride) {
    float4 v = ((const float4*)X)[i];
    ushort4 w;
    w.x = f2bf(v.x); w.y = f2bf(v.y); w.z = f2bf(v.z); w.w = f2bf(v.w);
    ((ushort4*)Xbf)[i] = w;
  }
  for (int i = tid; i < (HID * HID) / 4; i += stride) {
    float4 v = ((const float4*)Wq)[i];
    ushort4 w;
    w.x = f2bf(v.x); w.y = f2bf(v.y); w.z = f2bf(v.z); w.w = f2bf(v.w);
    ((ushort4*)Wbf)[i] = w;
    v = ((const float4*)Wk)[i];
    w.x = f2bf(v.x); w.y = f2bf(v.y); w.z = f2bf(v.z); w.w = f2bf(v.w);
    ((ushort4*)(Wbf + HID * HID))[i] = w;
    v = ((const float4*)Wv)[i];
    w.x = f2bf(v.x); w.y = f2bf(v.y); w.z = f2bf(v.z); w.w = f2bf(v.w);
    ((ushort4*)(Wbf + 2 * HID * HID))[i] = w;
  }
}

// Pure-bf16 projection: Y[m][c] = sum_k Xbf[m][k] * Wbf[c][k].
// Q,K stored [b][h][n][d]; V stored TRANSPOSED [b][h][d][n].
__global__ __launch_bounds__(256) void qkv_proj_bf(
    const unsigned short* __restrict__ Xbf, const unsigned short* __restrict__ Wbf,
    unsigned short* __restrict__ Y) {
  const unsigned short* W = Wbf + (size_t)blockIdx.y * (HID * HID);
  unsigned short* Yo = Y + (size_t)blockIdx.y * (NB * NHEAD * NA * DH);
  const int wave = threadIdx.x >> 6, lane = threadIdx.x & 63;
  const int lr = lane & 15, lh = lane >> 4;
  const int m0 = blockIdx.x * 32;
  const int cb = wave * 64;
  const floatx4 z = {0.f, 0.f, 0.f, 0.f};
  floatx4 acc[2][4];
#pragma unroll
  for (int i = 0; i < 2; i++)
#pragma unroll
    for (int j = 0; j < 4; j++) acc[i][j] = z;

  for (int kb = 0; kb < HID; kb += 32) {
    short8 a[2], bw[4];
#pragma unroll
    for (int rt = 0; rt < 2; rt++)
      a[rt] = *(const short8*)&Xbf[(size_t)(m0 + rt * 16 + lr) * HID + kb + lh * 8];
#pragma unroll
    for (int ci = 0; ci < 4; ci++)
      bw[ci] = *(const short8*)&W[(size_t)(cb + ci * 16 + lr) * HID + kb + lh * 8];
#pragma unroll
    for (int rt = 0; rt < 2; rt++)
#pragma unroll
      for (int ci = 0; ci < 4; ci++)
        acc[rt][ci] = mfma16(a[rt], bw[ci], acc[rt][ci]);
  }
  if (blockIdx.y == 2) {
    // V: [b][h][d][n], 4 consecutive n (rows m..m+3) packed per store.
#pragma unroll
    for (int rt = 0; rt < 2; rt++)
#pragma unroll
      for (int ci = 0; ci < 4; ci++) {
        int m = m0 + rt * 16 + lh * 4;       // rows m..m+3 (same batch: 32|512)
        int c = cb + ci * 16 + lr;
        int bb = m >> 9, n0 = m & 511, hh = c >> 5, dd = c & 31;
        ushort4 w;
        w.x = f2bf(acc[rt][ci][0]);
        w.y = f2bf(acc[rt][ci][1]);
        w.z = f2bf(acc[rt][ci][2]);
        w.w = f2bf(acc[rt][ci][3]);
        *(ushort4*)&Yo[((size_t)(bb * NHEAD + hh) * DH + dd) * NA + n0] = w;
      }
  } else {
#pragma unroll
    for (int rt = 0; rt < 2; rt++)
#pragma unroll
      for (int ci = 0; ci < 4; ci++)
#pragma unroll
        for (int r = 0; r < 4; r++) {
          int m = m0 + rt * 16 + lh * 4 + r;   // D layout: row=(l>>4)*4+reg
          int c = cb + ci * 16 + lr;           //           col=l&15
          int bb = m >> 9, n = m & 511, hh = c >> 5, dd = c & 31;
          Yo[((size_t)(bb * NHEAD + hh) * NA + n) * DH + dd] = f2bf(acc[rt][ci][r]);
        }
  }
}

// Fallback projection (R14): inline f32->bf16. Used only if ws too small.
__global__ __launch_bounds__(256) void qkv_proj(
    const float* __restrict__ X, const float* __restrict__ Wq,
    const float* __restrict__ Wk, const float* __restrict__ Wv,
    unsigned short* __restrict__ Y) {
  const float* W = (blockIdx.y == 0) ? Wq : (blockIdx.y == 1) ? Wk : Wv;
  unsigned short* Yo = Y + (size_t)blockIdx.y * (NB * NHEAD * NA * DH);
  const int wave = threadIdx.x >> 6, lane = threadIdx.x & 63;
  const int lr = lane & 15, lh = lane >> 4;
  const int m0 = blockIdx.x * 32;
  const int cb = wave * 64;
  const floatx4 z = {0.f, 0.f, 0.f, 0.f};
  floatx4 acc[2][4];
#pragma unroll
  for (int i = 0; i < 2; i++)
#pragma unroll
    for (int j = 0; j < 4; j++) acc[i][j] = z;

  for (int kb = 0; kb < HID; kb += 32) {
    short8 a[2], bw[4];
#pragma unroll
    for (int rt = 0; rt < 2; rt++)
      a[rt] = ld8f32_bf16(X + (size_t)(m0 + rt * 16 + lr) * HID + kb + lh * 8);
#pragma unroll
    for (int ci = 0; ci < 4; ci++)
      bw[ci] = ld8f32_bf16(W + (size_t)(cb + ci * 16 + lr) * HID + kb + lh * 8);
#pragma unroll
    for (int rt = 0; rt < 2; rt++)
#pragma unroll
      for (int ci = 0; ci < 4; ci++)
        acc[rt][ci] = mfma16(a[rt], bw[ci], acc[rt][ci]);
  }
  if (blockIdx.y == 2) {
#pragma unroll
    for (int rt = 0; rt < 2; rt++)
#pragma unroll
      for (int ci = 0; ci < 4; ci++) {
        int m = m0 + rt * 16 + lh * 4;
        int c = cb + ci * 16 + lr;
        int bb = m >> 9, n0 = m & 511, hh = c >> 5, dd = c & 31;
        ushort4 w;
        w.x = f2bf(acc[rt][ci][0]);
        w.y = f2bf(acc[rt][ci][1]);
        w.z = f2bf(acc[rt][ci][2]);
        w.w = f2bf(acc[rt][ci][3]);
        *(ushort4*)&Yo[((size_t)(bb * NHEAD + hh) * DH + dd) * NA + n0] = w;
      }
  } else {
#pragma unroll
    for (int rt = 0; rt < 2; rt++)
#pragma unroll
      for (int ci = 0; ci < 4; ci++)
#pragma unroll
        for (int r = 0; r < 4; r++) {
          int m = m0 + rt * 16 + lh * 4 + r;
          int c = cb + ci * 16 + lr;
          int bb = m >> 9, n = m & 511, hh = c >> 5, dd = c & 31;
          Yo[((size_t)(bb * NHEAD + hh) * NA + n) * DH + dd] = f2bf(acc[rt][ci][r]);
        }
  }
}

// grid: (32 q-blocks of 16 rows, 16 batch) = 512 blocks (2/CU exact), 512 thr.
// Wave h handles head h over all 512 keys (4 tiles of 128, online softmax).
// Bias tile (adj+mask merged) double-buffered in LDS, staged by all 512 threads.
__global__ __launch_bounds__(512, 4) void attn_fused(
    const unsigned short* __restrict__ Qw, const unsigned short* __restrict__ Kw,
    const unsigned short* __restrict__ Vtg, const float* __restrict__ X,
    const unsigned char* __restrict__ maskB, const int* __restrict__ maskI,
    const float* __restrict__ adj, float* __restrict__ out) {
  __shared__ float adj_lds[2][16][ADJ_LD];  // 2 x 8448 B
  const int qb = blockIdx.x, b = blockIdx.y;
  const int t = threadIdx.x;
  const int h = t >> 6, lane = t & 63, lr = lane & 15, lh = lane >> 4;
  const int q0 = qb * 16;
  const size_t bh = (size_t)(b * NHEAD + h) * NA * DH;
  const unsigned short* Kg = Kw + bh;
  const unsigned short* Vg = Vtg + bh;  // [d][n]: d*NA + n

  // mask dtype detect (wave-level over first 512 words; wave-uniform result).
  const unsigned int* mu = (const unsigned int*)maskB;
  unsigned int cnt = 0;
#pragma unroll
  for (int j = 0; j < 8; j++) cnt += (mu[lane + j * 64] != 0u) ? 1u : 0u;
#pragma unroll
  for (int off = 32; off > 0; off >>= 1) cnt += __shfl_xor(cnt, off);
  const bool mBytes = (cnt > 368u);

  // staging: thread t owns float4 #t of the 16x128 bias tile.
  const int srow = t >> 5, sc4 = (t & 31) * 4;
  const size_t srowoff = ((size_t)b * NA + q0 + srow) * NA;

  {  // prologue: stage tile 0 (mask merged: masked -> -1e30)
    float4 av = *(const float4*)&adj[srowoff + sc4];
    if (mBytes) {
      uchar4 mb = *(const uchar4*)&maskB[srowoff + sc4];
      if (mb.x) av.x = -1e30f;
      if (mb.y) av.y = -1e30f;
      if (mb.z) av.z = -1e30f;
      if (mb.w) av.w = -1e30f;
    } else {
      int4 mi = *(const int4*)&maskI[srowoff + sc4];
      if (mi.x) av.x = -1e30f;
      if (mi.y) av.y = -1e30f;
      if (mi.z) av.z = -1e30f;
      if (mi.w) av.w = -1e30f;
    }
    *(float4*)&adj_lds[0][srow][sc4] = av;
  }
  __syncthreads();

  short8 qf = *(const short8*)&Qw[bh + (size_t)(q0 + lr) * DH + lh * 8];
  const floatx4 z = {0.f, 0.f, 0.f, 0.f};

  float m_run = -3.0e38f, l_run = 0.f;  // state for q = q0 + lr (S^T layout)
  floatx4 o0 = z, o1 = z;               // rows q0 + lh*4 + r (C/D layout)

#pragma unroll
  for (int tile = 0; tile < 4; ++tile) {
    const int cur = tile & 1;
    const int keyoff = tile * 128;

    // issue next-tile bias loads early (vmcnt waits after compute)
    float4 nav;
    uchar4 nmbB;
    int4 nmbI;
    if (tile < 3) {
      const int nko = (tile + 1) * 128;
      nav = *(const float4*)&adj[srowoff + nko + sc4];
      if (mBytes) nmbB = *(const uchar4*)&maskB[srowoff + nko + sc4];
      else        nmbI = *(const int4*)&maskI[srowoff + nko + sc4];
    }

    // S^T = K * Q^T: lane holds col q=lr, rows key=keyoff+kt*16+lh*4+r
    floatx4 s[8];
#pragma unroll
    for (int kt = 0; kt < 8; kt++) s[kt] = z;
#pragma unroll
    for (int kt = 0; kt < 8; kt++) {
      short8 kf = *(const short8*)&Kg[(size_t)(keyoff + kt * 16 + lr) * DH + lh * 8];
      s[kt] = mfma16(kf, qf, s[kt]);
    }

    float pmax = -3.0e38f;
#pragma unroll
    for (int kt = 0; kt < 8; kt++) {
      float4 av = *(const float4*)&adj_lds[cur][lr][kt * 16 + lh * 4];
      float v0 = s[kt][0] * INV_TP + av.x;
      float v1 = s[kt][1] * INV_TP + av.y;
      float v2 = s[kt][2] * INV_TP + av.z;
      float v3 = s[kt][3] * INV_TP + av.w;
      s[kt][0] = v0; s[kt][1] = v1; s[kt][2] = v2; s[kt][3] = v3;
      pmax = fmaxf(pmax, fmaxf(fmaxf(v0, v1), fmaxf(v2, v3)));
    }
    pmax = fmaxf(pmax, __shfl_xor(pmax, 16));
    pmax = fmaxf(pmax, __shfl_xor(pmax, 32));

    const float mnew = fmaxf(m_run, pmax);
    if (tile) {  // tile 0: o/l are zero, skip rescale
      const float corr = __expf(m_run - mnew);
      l_run *= corr;
#pragma unroll
      for (int r = 0; r < 4; r++) {
        float c = __shfl(corr, lh * 4 + r, 64);
        o0[r] *= c;
        o1[r] *= c;
      }
    }
    m_run = mnew;

    float sum = 0.f;
#pragma unroll
    for (int kt = 0; kt < 8; kt++) {
      float e0 = __expf(s[kt][0] - mnew);
      float e1 = __expf(s[kt][1] - mnew);
      float e2 = __expf(s[kt][2] - mnew);
      float e3 = __expf(s[kt][3] - mnew);
      s[kt][0] = e0; s[kt][1] = e1; s[kt][2] = e2; s[kt][3] = e3;
      sum += (e0 + e1) + (e2 + e3);
    }
    sum += __shfl_xor(sum, 16);
    sum += __shfl_xor(sum, 32);
    l_run += sum;

    // PV, relabeled K-dim: slot lh*8+j <-> key keyoff+32kc+(j<4 ? lh*4+j : 16+lh*4+j-4).
#pragma unroll
    for (int kc = 0; kc < 4; kc++) {
      union { short8 s8; unsigned int u[4]; } aa;
      aa.u[0] = (unsigned int)f2bf(s[2 * kc][0]) |
                ((unsigned int)f2bf(s[2 * kc][1]) << 16);
      aa.u[1] = (unsigned int)f2bf(s[2 * kc][2]) |
                ((unsigned int)f2bf(s[2 * kc][3]) << 16);
      aa.u[2] = (unsigned int)f2bf(s[2 * kc + 1][0]) |
                ((unsigned int)f2bf(s[2 * kc + 1][1]) << 16);
      aa.u[3] = (unsigned int)f2bf(s[2 * kc + 1][2]) |
                ((unsigned int)f2bf(s[2 * kc + 1][3]) << 16);
      const int kbase = keyoff + kc * 32 + lh * 4;
      union { short8 s8; uint2 u2[2]; } v0f, v1f;
      v0f.u2[0] = *(const uint2*)&Vg[(size_t)lr * NA + kbase];
      v0f.u2[1] = *(const uint2*)&Vg[(size_t)lr * NA + kbase + 16];
      v1f.u2[0] = *(const uint2*)&Vg[(size_t)(16 + lr) * NA + kbase];
      v1f.u2[1] = *(const uint2*)&Vg[(size_t)(16 + lr) * NA + kbase + 16];
      o0 = mfma16(aa.s8, v0f.s8, o0);
      o1 = mfma16(aa.s8, v1f.s8, o1);
    }

    // write staged tile t+1 into the other buffer, then block barrier
    if (tile < 3) {
      if (mBytes) {
        if (nmbB.x) nav.x = -1e30f;
        if (nmbB.y) nav.y = -1e30f;
        if (nmbB.z) nav.z = -1e30f;
        if (nmbB.w) nav.w = -1e30f;
      } else {
        if (nmbI.x) nav.x = -1e30f;
        if (nmbI.y) nav.y = -1e30f;
        if (nmbI.z) nav.z = -1e30f;
        if (nmbI.w) nav.w = -1e30f;
      }
      *(float4*)&adj_lds[cur ^ 1][srow][sc4] = nav;
    }
    __syncthreads();
  }

  const float inv = 1.0f / l_run;  // for q = q0 + lr
#pragma unroll
  for (int r = 0; r < 4; r++) {
    float iv = __shfl(inv, lh * 4 + r, 64);  // row q0+lh*4+r's normalizer
    size_t idx = ((size_t)b * NA + (q0 + lh * 4 + r)) * HID + h * DH + lr;
    out[idx] = o0[r] * iv + X[idx];
    out[idx + 16] = o1[r] * iv + X[idx + 16];
  }
}

extern "C" void kernel_launch(void* const* d_in, const int* in_sizes, int n_in,
                              void* d_out, int out_size, void* d_ws, size_t ws_size,
                              hipStream_t stream) {
  const float* x = (const float*)d_in[0];
  const void* mask = d_in[1];
  const float* adj = (const float*)d_in[2];
  const float* Wq = (const float*)d_in[3];
  const float* Wk = (const float*)d_in[4];
  const float* Wv = (const float*)d_in[5];
  float* out = (float*)d_out;

  char* ws = (char*)d_ws;
  const size_t MB = 1048576;
  const size_t NEED = 4 * MB + 512 * 1024 + 3 * 4 * MB;  // Xbf + Wbf + QKV = 16.5MB

  unsigned short *Qw, *Kw, *Vw;
  if (ws_size >= NEED) {
    unsigned short* Xbf = (unsigned short*)ws;                   // 4 MB
    unsigned short* Wbf = (unsigned short*)(ws + 4 * MB);        // 384 KB (+pad)
    Qw = (unsigned short*)(ws + 4 * MB + 512 * 1024);            // 4 MB
    Kw = (unsigned short*)(ws + 8 * MB + 512 * 1024);            // 4 MB
    Vw = (unsigned short*)(ws + 12 * MB + 512 * 1024);           // 4 MB (transposed)
    cvt_bf16<<<1024, 256, 0, stream>>>(x, Wq, Wk, Wv, Xbf, Wbf);
    qkv_proj_bf<<<dim3(256, 3), 256, 0, stream>>>(Xbf, Wbf, Qw);
  } else {
    Qw = (unsigned short*)(ws + 4096);
    Kw = (unsigned short*)(ws + 4096 + 4 * MB);
    Vw = (unsigned short*)(ws + 4096 + 8 * MB);
    qkv_proj<<<dim3(256, 3), 256, 0, stream>>>(x, Wq, Wk, Wv, Qw);
  }
  attn_fused<<<dim3(32, NB), 512, 0, stream>>>(
      Qw, Kw, Vw, x, (const unsigned char*)mask, (const int*)mask, adj, out);
}